// Round 9
// baseline (413.762 us; speedup 1.0000x reference)
//
#include <hip/hip_runtime.h>

typedef unsigned short ushort_t;
typedef float v2f __attribute__((ext_vector_type(2)));

__device__ __forceinline__ float u2f(ushort_t u){
    union{unsigned int i; float f;} x; x.i = ((unsigned int)u) << 16; return x.f;
}
__device__ __forceinline__ ushort_t f2u(float f){   // f32 -> bf16 bits, RNE
    union{float fl; unsigned int i;} x; x.fl = f;
    unsigned int r = x.i + 0x7FFFu + ((x.i >> 16) & 1u);
    return (ushort_t)(r >> 16);
}

#define REP10(M) M(0)M(1)M(2)M(3)M(4)M(5)M(6)M(7)M(8)M(9)
#define REP16(M) M(0)M(1)M(2)M(3)M(4)M(5)M(6)M(7)M(8)M(9)M(10)M(11)M(12)M(13)M(14)M(15)
#define REP22(M) REP16(M) M(16)M(17)M(18)M(19)M(20)M(21)
#define REP55(M) M(0)M(1)M(2)M(3)M(4)M(5)M(6)M(7)M(8)M(9)M(10)M(11)M(12)M(13)M(14)M(15)M(16)M(17)M(18)M(19)M(20)M(21)M(22)M(23)M(24)M(25)M(26)M(27)M(28)M(29)M(30)M(31)M(32)M(33)M(34)M(35)M(36)M(37)M(38)M(39)M(40)M(41)M(42)M(43)M(44)M(45)M(46)M(47)M(48)M(49)M(50)M(51)M(52)M(53)M(54)

// ================= Kernel 1: h = x@cw+cb ; 4x { h += LN16(h@pw+pb) } -> ws bf16 ===
// Channel attention collapses (softmax rows sum to 1 -> einsum == identity on x).
// X staged through LDS: coalesced float2 global loads -> stride-23-padded rows ->
// conflict-free per-thread reads. All math in named scalars (no scratch).
__global__ __launch_bounds__(256)
void k_embed(const float* __restrict__ X,
             const float* __restrict__ CW, const float* __restrict__ CB,
             const float* __restrict__ PW, const float* __restrict__ PB,
             const float* __restrict__ PG, const float* __restrict__ PBE,
             ushort_t* __restrict__ Hws)
{
    __shared__ float sX[256*23];   // 256 rows, stride 23 (odd -> 2-way max, free)
    const int t = threadIdx.x;
    const int base = blockIdx.x * 256;          // first row of this block (grid exact)

    {   // coalesced stage: 256 rows x 22 floats = 2816 float2
        const float2* src = (const float2*)(X + (size_t)base * 22);
        for (int i = t; i < 2816; i += 256){
            int r = i / 11, c = (i - r*11) * 2;
            float2 v = src[i];
            sX[r*23 + c] = v.x; sX[r*23 + c + 1] = v.y;
        }
    }
    __syncthreads();

    const int idx = base + t;
    const int b = idx / 1000, s = idx - b * 1000;
    const float* xp = sX + t*23;

#define E_DX(j) const float x##j = xp[j];
    REP22(E_DX)
#define E_DV(c) float v##c = CB[c];
    REP16(E_DV)
#define E_CH(j) { const float xx = x##j; const float* w = CW + (j)*16; \
    v0+=xx*w[0]; v1+=xx*w[1]; v2+=xx*w[2]; v3+=xx*w[3]; \
    v4+=xx*w[4]; v5+=xx*w[5]; v6+=xx*w[6]; v7+=xx*w[7]; \
    v8+=xx*w[8]; v9+=xx*w[9]; v10+=xx*w[10]; v11+=xx*w[11]; \
    v12+=xx*w[12]; v13+=xx*w[13]; v14+=xx*w[14]; v15+=xx*w[15]; }
    REP22(E_CH)

#define E_DU(c) float u##c = PB[c];
#define E_PJ(j) { const float vv = v##j; const float* w = PW + (j)*16; \
    u0+=vv*w[0]; u1+=vv*w[1]; u2+=vv*w[2]; u3+=vv*w[3]; \
    u4+=vv*w[4]; u5+=vv*w[5]; u6+=vv*w[6]; u7+=vv*w[7]; \
    u8+=vv*w[8]; u9+=vv*w[9]; u10+=vv*w[10]; u11+=vv*w[11]; \
    u12+=vv*w[12]; u13+=vv*w[13]; u14+=vv*w[14]; u15+=vv*w[15]; }
#define E_DS(c) const float d##c = u##c - m;
#define E_UP(c) v##c += d##c * inv * PG[c] + PBE[c];
#define E_LNIT { \
    REP16(E_DU) REP16(E_PJ) \
    float m = (((u0+u1)+(u2+u3))+((u4+u5)+(u6+u7)))+(((u8+u9)+(u10+u11))+((u12+u13)+(u14+u15))); \
    m *= 0.0625f; \
    REP16(E_DS) \
    float var = (((d0*d0+d1*d1)+(d2*d2+d3*d3))+((d4*d4+d5*d5)+(d6*d6+d7*d7)))+(((d8*d8+d9*d9)+(d10*d10+d11*d11))+((d12*d12+d13*d13)+(d14*d14+d15*d15))); \
    var *= 0.0625f; \
    float inv = rsqrtf(var + 1e-5f); \
    REP16(E_UP) }

    E_LNIT E_LNIT E_LNIT E_LNIT

    ushort_t* hp = Hws + b*16000 + s;
#define E_ST(c) hp[(c)*1000] = f2u(v##c);
    REP16(E_ST)
}

// ================= Kernel 2: conv1+BN+LReLU fused into conv2 -> t (ws f32) ========
__global__ __launch_bounds__(256)
void k_conv(const ushort_t* __restrict__ Hws,
            const float* __restrict__ W1, const float* __restrict__ B1,
            const float* __restrict__ BNG, const float* __restrict__ BNB,
            const float* __restrict__ BNM, const float* __restrict__ BNV,
            const float* __restrict__ W2, const float* __restrict__ B2,
            float* __restrict__ Tws)
{
    __shared__ ushort_t sH[16000];   // h[16][1000] bf16 = 32 KB
    const int tid = threadIdx.x, b = blockIdx.x;

    {   // coalesced stage, 16B/lane (b*32000 bytes is 16-aligned)
        const uint4* src = (const uint4*)(Hws + b*16000);
        uint4* dst = (uint4*)sH;
        for (int i = tid; i < 2000; i += 256) dst[i] = src[i];
    }
    const float sc0 = BNG[0]*rsqrtf(BNV[0]+1e-5f);
    const float sc1 = BNG[1]*rsqrtf(BNV[1]+1e-5f);
    const float sh0 = BNB[0] + (B1[0]-BNM[0])*sc0;
    const float sh1 = BNB[1] + (B1[1]-BNM[1])*sc1;
    __syncthreads();

    if (tid < 190){
        const int w5 = tid*5;
#define C_DT(o) float t##o = B2[o];
        REP10(C_DT)
        const float* w1a = W1;
        const float* w1b = W1 + 51;
        for (int kh = 0; kh < 16; ++kh){
            const ushort_t* hp = sH + kh*1000 + w5;
            float a0=0.f,a1=0.f,a2=0.f,a3=0.f,a4=0.f;
            float b0_=0.f,b1_=0.f,b2_=0.f,b3_=0.f,b4_=0.f;
#define C_TAP(e) { const float cur = u2f(hp[e]); \
            if ((e) < 51)              { a0+=cur*w1a[(e)];   b0_+=cur*w1b[(e)];   } \
            if ((e) >= 1 && (e) < 52)  { a1+=cur*w1a[(e)-1]; b1_+=cur*w1b[(e)-1]; } \
            if ((e) >= 2 && (e) < 53)  { a2+=cur*w1a[(e)-2]; b2_+=cur*w1b[(e)-2]; } \
            if ((e) >= 3 && (e) < 54)  { a3+=cur*w1a[(e)-3]; b3_+=cur*w1b[(e)-3]; } \
            if ((e) >= 4)              { a4+=cur*w1a[(e)-4]; b4_+=cur*w1b[(e)-4]; } }
            REP55(C_TAP)
#define C_LR(q) { a##q = a##q*sc0 + sh0; a##q = a##q > 0.f ? a##q : 0.2f*a##q; \
                  b##q##_ = b##q##_*sc1 + sh1; b##q##_ = b##q##_ > 0.f ? b##q##_ : 0.2f*b##q##_; }
            C_LR(0) C_LR(1) C_LR(2) C_LR(3) C_LR(4)
#define C_C2(o) { const float* wa = W2 + (((o)*2  )*16 + kh)*5; \
                  const float* wb = W2 + (((o)*2+1)*16 + kh)*5; \
        t##o += a0*wa[0]+a1*wa[1]+a2*wa[2]+a3*wa[3]+a4*wa[4] \
              + b0_*wb[0]+b1_*wb[1]+b2_*wb[2]+b3_*wb[3]+b4_*wb[4]; }
            REP10(C_C2)
        }
        float* op = Tws + (size_t)b*1900 + tid*10;
#define C_ST(o) op[o] = t##o;
        REP10(C_ST)
    }
}

// ================= Kernel 3: 3 transformer layers (n=190, e=10, 5 heads, d=2) =====
// Phase 2 uses packed-f32 (v_pk_fma_f32) on query pairs + exp2 with prescaled q.
__global__ __launch_bounds__(256)
void k_tf(const float* __restrict__ Tws,
          const float* __restrict__ LN1G, const float* __restrict__ LN1B,
          const float* __restrict__ QW, const float* __restrict__ QBv,
          const float* __restrict__ KW, const float* __restrict__ KBv,
          const float* __restrict__ VW, const float* __restrict__ VBv,
          const float* __restrict__ OW, const float* __restrict__ OBv,
          const float* __restrict__ LN2G, const float* __restrict__ LN2B,
          const float* __restrict__ F1W, const float* __restrict__ F1B,
          const float* __restrict__ F2W, const float* __restrict__ F2B,
          float* __restrict__ OUT)
{
    __shared__ __align__(16) float T [190*11];
    __shared__ __align__(16) float QB[190*12];
    __shared__ __align__(16) float KB[190*12];
    __shared__ __align__(16) float VB[190*12];
    __shared__ __align__(16) float AT[190*12];

    const int tid = threadIdx.x, b = blockIdx.x;
    for (int i = tid; i < 1900; i += 256){
        int r = i/10, c = i - r*10;
        T[r*11 + c] = Tws[(size_t)b*1900 + i];
    }
    __syncthreads();

    // 1/sqrt(10) * log2(e): prescale so logits feed exp2 directly
    const float LSCALE = (float)(0.31622776601683794 * 1.4426950408889634);
    const bool act = (tid < 190);
#pragma unroll 1
    for (int L = 0; L < 3; ++L){
        const float* ln1g = LN1G + L*10; const float* ln1b = LN1B + L*10;
        const float* qw = QW + L*100;    const float* qb = QBv + L*10;
        const float* kw = KW + L*100;    const float* kb = KBv + L*10;
        const float* vw = VW + L*100;    const float* vb = VBv + L*10;
        const float* ow = OW + L*100;    const float* ob = OBv + L*10;
        const float* ln2g = LN2G + L*10; const float* ln2b = LN2B + L*10;
        const float* f1w = F1W + L*400;  const float* f1b = F1B + L*40;
        const float* f2w = F2W + L*400;  const float* f2b = F2B + L*10;

        // ---- phase 1: LN1 + Q/K/V projections ----
        if (act){
#define T_TV(c) float tv##c = T[tid*11 + c];
            REP10(T_TV)
            float m = (((tv0+tv1)+(tv2+tv3))+((tv4+tv5)+(tv6+tv7)))+(tv8+tv9);
            m *= 0.1f;
#define T_D1(c) const float e1##c = tv##c - m;
            REP10(T_D1)
            float var = (((e10*e10+e11*e11)+(e12*e12+e13*e13))+((e14*e14+e15*e15)+(e16*e16+e17*e17)))+(e18*e18+e19*e19);
            var *= 0.1f;
            float inv = rsqrtf(var + 1e-5f);
#define T_Y(c) const float y##c = e1##c*inv*ln1g[c] + ln1b[c];
            REP10(T_Y)
#define T_PQ(c) { float aq = qb[c] + y0*qw[c] + y1*qw[10+c] + y2*qw[20+c] + y3*qw[30+c] + y4*qw[40+c] \
                           + y5*qw[50+c] + y6*qw[60+c] + y7*qw[70+c] + y8*qw[80+c] + y9*qw[90+c]; \
                  QB[tid*12 + c] = aq; }
            REP10(T_PQ)
#define T_PK(c) { float ak = kb[c] + y0*kw[c] + y1*kw[10+c] + y2*kw[20+c] + y3*kw[30+c] + y4*kw[40+c] \
                           + y5*kw[50+c] + y6*kw[60+c] + y7*kw[70+c] + y8*kw[80+c] + y9*kw[90+c]; \
                  KB[tid*12 + c] = ak; }
            REP10(T_PK)
#define T_PV(c) { float av = vb[c] + y0*vw[c] + y1*vw[10+c] + y2*vw[20+c] + y3*vw[30+c] + y4*vw[40+c] \
                           + y5*vw[50+c] + y6*vw[60+c] + y7*vw[70+c] + y8*vw[80+c] + y9*vw[90+c]; \
                  VB[tid*12 + c] = av; }
            REP10(T_PV)
        }
        __syncthreads();

        // ---- phase 2: attention, head-major, packed query-pairs ----
        // no-max softmax: logits O(1); jax's max-shift is mathematically identity.
        if (tid < 240){
            const int h5 = tid / 48;
            const int qg = tid - h5*48;
            const int q0 = qg * 4;
#define T_LQ(i) float qx##i, qy##i; { const int qi = q0 + i; \
            if (qi < 190){ qx##i = QB[qi*12 + 2*h5]*LSCALE; qy##i = QB[qi*12 + 2*h5 + 1]*LSCALE; } \
            else { qx##i = 0.f; qy##i = 0.f; } }
            T_LQ(0) T_LQ(1) T_LQ(2) T_LQ(3)
            v2f qxA = {qx0, qx1}, qxB = {qx2, qx3};
            v2f qyA = {qy0, qy1}, qyB = {qy2, qy3};
            v2f lA = {0.f,0.f}, lB = {0.f,0.f};
            v2f pxA = {0.f,0.f}, pxB = {0.f,0.f};
            v2f pyA = {0.f,0.f}, pyB = {0.f,0.f};
            const float* kp = KB + 2*h5;
            const float* vp = VB + 2*h5;
            for (int kk = 0; kk < 190; ++kk){
                const float2 kv = *(const float2*)(kp + kk*12);
                const float2 vv = *(const float2*)(vp + kk*12);
                const v2f kx = {kv.x, kv.x}, ky = {kv.y, kv.y};
                v2f dA = qxA*kx + qyA*ky;            // v_pk_mul + v_pk_fma
                v2f dB = qxB*kx + qyB*ky;
                v2f eA = {exp2f(dA.x), exp2f(dA.y)}; // v_exp_f32 x2
                v2f eB = {exp2f(dB.x), exp2f(dB.y)};
                lA += eA; lB += eB;                  // v_pk_add
                const v2f vx = {vv.x, vv.x}, vy = {vv.y, vv.y};
                pxA += eA*vx; pxB += eB*vx;          // v_pk_fma
                pyA += eA*vy; pyB += eB*vy;
            }
#define T_SA(i, vec, fld) { const int qi = q0 + i; if (qi < 190){ \
                const float rl = 1.f/l##vec.fld; \
                AT[qi*12 + 2*h5] = px##vec.fld*rl; AT[qi*12 + 2*h5 + 1] = py##vec.fld*rl; } }
            T_SA(0, A, x) T_SA(1, A, y) T_SA(2, B, x) T_SA(3, B, y)
        }
        __syncthreads();

        // ---- phase 3: out-proj + residual + LN2 + FF(GELU exact) + residual ----
        if (act){
#define T_TV2(c) float w##c = T[tid*11 + c];
            REP10(T_TV2)
#define T_AT(c) const float at##c = AT[tid*12 + c];
            REP10(T_AT)
#define T_OP(c) w##c += ob[c] + at0*ow[c] + at1*ow[10+c] + at2*ow[20+c] + at3*ow[30+c] + at4*ow[40+c] \
                       + at5*ow[50+c] + at6*ow[60+c] + at7*ow[70+c] + at8*ow[80+c] + at9*ow[90+c];
            REP10(T_OP)
            float m2 = (((w0+w1)+(w2+w3))+((w4+w5)+(w6+w7)))+(w8+w9);
            m2 *= 0.1f;
#define T_D2(c) const float e2##c = w##c - m2;
            REP10(T_D2)
            float var2 = (((e20*e20+e21*e21)+(e22*e22+e23*e23))+((e24*e24+e25*e25)+(e26*e26+e27*e27)))+(e28*e28+e29*e29);
            var2 *= 0.1f;
            float inv2 = rsqrtf(var2 + 1e-5f);
#define T_Z(c) const float z##c = e2##c*inv2*ln2g[c] + ln2b[c];
            REP10(T_Z)
#define T_DD(c) float dd##c = f2b[c];
            REP10(T_DD)
#pragma unroll 4
            for (int j = 0; j < 40; ++j){
                float aj = f1b[j] + z0*f1w[j] + z1*f1w[40+j] + z2*f1w[80+j] + z3*f1w[120+j] + z4*f1w[160+j]
                         + z5*f1w[200+j] + z6*f1w[240+j] + z7*f1w[280+j] + z8*f1w[320+j] + z9*f1w[360+j];
                const float gj = 0.5f * aj * (1.f + erff(aj * 0.70710678118654752f));
                const float* w2p = f2w + j*10;
                dd0 += gj*w2p[0]; dd1 += gj*w2p[1]; dd2 += gj*w2p[2]; dd3 += gj*w2p[3]; dd4 += gj*w2p[4];
                dd5 += gj*w2p[5]; dd6 += gj*w2p[6]; dd7 += gj*w2p[7]; dd8 += gj*w2p[8]; dd9 += gj*w2p[9];
            }
#define T_WB(c) T[tid*11 + c] = w##c + dd##c;
            REP10(T_WB)
        }
        __syncthreads();
    }

    if (act){
        float* op = OUT + (size_t)b*1900 + tid*10;
#define T_OUT(c) op[c] = T[tid*11 + c];
        REP10(T_OUT)
    }
}

extern "C" void kernel_launch(void* const* d_in, const int* in_sizes, int n_in,
                              void* d_out, int out_size, void* d_ws, size_t ws_size,
                              hipStream_t stream)
{
    (void)ws_size; (void)n_in; (void)out_size;
    const int B = in_sizes[0] / 22000;   // 512
    auto in = [&](int i){ return (const float*)d_in[i]; };
    ushort_t* Hws = (ushort_t*)d_ws;                              // B*16000 bf16 = 16.38 MB
    float*    Tws = (float*)((char*)d_ws + (size_t)B*16000*2);    // B*1900 f32

    k_embed<<<(B*1000 + 255)/256, 256, 0, stream>>>(
        in(0), in(1), in(2), in(11), in(12), in(13), in(14), Hws);

    k_conv<<<B, 256, 0, stream>>>(
        Hws, in(15), in(16), in(17), in(18), in(19), in(20), in(21), in(22), Tws);

    k_tf<<<B, 256, 0, stream>>>(
        Tws,
        in(23), in(24), in(25), in(26), in(27), in(28), in(29), in(30),
        in(31), in(32), in(33), in(34), in(35), in(36), in(37), in(38),
        (float*)d_out);
}